// Round 7
// baseline (44324.643 us; speedup 1.0000x reference)
//
#include <hip/hip_runtime.h>
#include <hip/hip_cooperative_groups.h>
#include <stdint.h>

namespace cg = cooperative_groups;

#define NB 512
#define NT 256

struct P {
    const float *actions, *embeds, *aw, *ab, *ag, *abt;
    const float *w_ih, *w_hh, *b_ih, *b_hh;
    const float *pr_w1, *pr_b1, *pr_g, *pr_bt, *pr_w2, *pr_b2;
    const float *po_w1, *po_b1, *po_g, *po_bt, *po_w2, *po_b2;
    float *out_states, *out_priors, *out_posts;
    float *WT;          // [1024][1536] w_ih stoch-part transposed
    double *deter;      // [512][512]
    double *gh, *gi;    // [512][1536]
    double *POraw;      // [512][512]
    double *PRraw;      // [512][512] (mode0 only)
    double *At0, *At1;  // [512][512]
    float *PH;          // [32768][512] (mode1 only)
    int *sidx;          // [512*32]
    int mode1;
};

// ---------------- math helpers (f64) ---------------------------------------

__device__ __forceinline__ double mish_d(double x) {
    double sp = fmax(x, 0.0) + log1p(exp(-fabs(x)));
    return x * tanh(sp);
}

// ---------------- threefry2x32 (JAX partitionable semantics) ----------------

__device__ __forceinline__ uint32_t rotl32(uint32_t v, int r) {
    return (v << r) | (v >> (32 - r));
}

__device__ __forceinline__ void tf2x32(uint32_t k0, uint32_t k1, uint32_t& x0, uint32_t& x1) {
    const uint32_t ks2 = k0 ^ k1 ^ 0x1BD11BDAu;
    const int ra[4] = {13, 15, 26, 6};
    const int rb[4] = {17, 29, 16, 24};
    x0 += k0; x1 += k1;
#pragma unroll
    for (int i = 0; i < 4; i++) { x0 += x1; x1 = rotl32(x1, ra[i]); x1 ^= x0; }
    x0 += k1; x1 += ks2 + 1u;
#pragma unroll
    for (int i = 0; i < 4; i++) { x0 += x1; x1 = rotl32(x1, rb[i]); x1 ^= x0; }
    x0 += ks2; x1 += k0 + 2u;
#pragma unroll
    for (int i = 0; i < 4; i++) { x0 += x1; x1 = rotl32(x1, ra[i]); x1 ^= x0; }
    x0 += k0; x1 += k1 + 3u;
#pragma unroll
    for (int i = 0; i < 4; i++) { x0 += x1; x1 = rotl32(x1, rb[i]); x1 ^= x0; }
    x0 += k1; x1 += ks2 + 4u;
#pragma unroll
    for (int i = 0; i < 4; i++) { x0 += x1; x1 = rotl32(x1, ra[i]); x1 ^= x0; }
    x0 += ks2; x1 += k0 + 5u;
}

// split(key,64)[t] = both outputs of tf(key,(0,t))
__device__ __forceinline__ void step_key(int t, uint32_t& ka, uint32_t& kb) {
    uint32_t x0 = 0u, x1 = (uint32_t)t;
    tf2x32(0u, 42u, x0, x1);
    ka = x0; kb = x1;
}

// bits_i = x0 ^ x1 of tf(key,(0,i))
__device__ __forceinline__ double gumbel_d(uint32_t n, uint32_t ka, uint32_t kb) {
    uint32_t x0 = 0u, x1 = n;
    tf2x32(ka, kb, x0, x1);
    uint32_t bits = x0 ^ x1;
    uint32_t fb = (bits >> 9) | 0x3f800000u;
    float f = __uint_as_float(fb) - 1.0f;
    double u = fmax((double)f, 1.17549435e-38);
    return -log(-log(u));
}

// ---------------- per-wave row ops ------------------------------------------

__device__ void act_row(const float* actions, const float* aw, const float* ab,
                        const float* ag, const float* abt, double* dst, int b, int t) {
    int l = threadIdx.x & 63;
    double x[8];
    double s = 0;
#pragma unroll
    for (int i = 0; i < 8; i++) {
        int h = l + 64 * i;
        double a = (double)ab[h];
        if (t > 0) {
            const float* ac = actions + ((long long)b * 64 + (t - 1)) * 32;
            #pragma unroll 4
            for (int k = 0; k < 32; k++)
                a += (double)ac[k] * (double)aw[h * 32 + k];
        }
        x[i] = a; s += a;
    }
#pragma unroll
    for (int m = 1; m < 64; m <<= 1) s += __shfl_xor(s, m);
    double mean = s * (1.0 / 512.0);
    double vv = 0;
#pragma unroll
    for (int i = 0; i < 8; i++) { double d = x[i] - mean; vv += d * d; }
#pragma unroll
    for (int m = 1; m < 64; m <<= 1) vv += __shfl_xor(vv, m);
    double inv = 1.0 / sqrt(vv * (1.0 / 512.0) + 1e-5);
#pragma unroll
    for (int i = 0; i < 8; i++) {
        int h = l + 64 * i;
        dst[h] = mish_d((x[i] - mean) * inv * (double)ag[h] + (double)abt[h]);
    }
}

__device__ void ln_row(double* row, const float* g, const float* bt) {
    int l = threadIdx.x & 63;
    double x[8];
    double s = 0;
#pragma unroll
    for (int i = 0; i < 8; i++) { x[i] = row[l + 64 * i]; s += x[i]; }
#pragma unroll
    for (int m = 1; m < 64; m <<= 1) s += __shfl_xor(s, m);
    double mean = s * (1.0 / 512.0);
    double vv = 0;
#pragma unroll
    for (int i = 0; i < 8; i++) { double d = x[i] - mean; vv += d * d; }
#pragma unroll
    for (int m = 1; m < 64; m <<= 1) vv += __shfl_xor(vv, m);
    double inv = 1.0 / sqrt(vv * (1.0 / 512.0) + 1e-5);
#pragma unroll
    for (int i = 0; i < 8; i++) {
        int h = l + 64 * i;
        row[h] = mish_d((x[i] - mean) * inv * (double)g[h] + (double)bt[h]);
    }
}

__device__ void ln_row_f32(float* row, const float* g, const float* bt) {
    int l = threadIdx.x & 63;
    double x[8];
    double s = 0;
#pragma unroll
    for (int i = 0; i < 8; i++) { x[i] = (double)row[l + 64 * i]; s += x[i]; }
#pragma unroll
    for (int m = 1; m < 64; m <<= 1) s += __shfl_xor(s, m);
    double mean = s * (1.0 / 512.0);
    double vv = 0;
#pragma unroll
    for (int i = 0; i < 8; i++) { double d = x[i] - mean; vv += d * d; }
#pragma unroll
    for (int m = 1; m < 64; m <<= 1) vv += __shfl_xor(vv, m);
    double inv = 1.0 / sqrt(vv * (1.0 / 512.0) + 1e-5);
#pragma unroll
    for (int i = 0; i < 8; i++) {
        int h = l + 64 * i;
        row[h] = (float)mish_d((x[i] - mean) * inv * (double)g[h] + (double)bt[h]);
    }
}

// ---------------- 32x32 vector-FMA tile (f64 accumulate) --------------------
// C[m][n] = sum_k A[m][k]*B[n][k]. A: k<asplit from Ad (f64), else Af (f32).
// thread (ty=tid>>3, tx=tid&7) owns row m0+ty, cols n0+tx*4..+3 -> c[4].

__device__ void run_tile_v(const double* Ad, long long ldad,
                           const float* Af, long long ldaf, int asplit,
                           const float* Bp, long long ldb, int K,
                           int m0, int n0,
                           double (*As)[17], float (*Bs)[17], double* c) {
    const int tid = threadIdx.x;
    const int ty = tid >> 3, tx = tid & 7;
    const int sr = tid >> 3, sk = (tid & 7) * 2;
    c[0] = c[1] = c[2] = c[3] = 0.0;
    for (int k0 = 0; k0 < K; k0 += 16) {
#pragma unroll
        for (int i = 0; i < 2; i++) {
            int k = k0 + sk + i;
            double v;
            if (k < asplit) v = Ad[(long long)(m0 + sr) * ldad + k];
            else            v = (double)Af[(long long)(m0 + sr) * ldaf + (k - asplit)];
            As[sr][sk + i] = v;
            Bs[sr][sk + i] = Bp[(long long)(n0 + sr) * ldb + k];
        }
        __syncthreads();
#pragma unroll
        for (int kk = 0; kk < 16; kk++) {
            double a = As[ty][kk];
            c[0] += a * (double)Bs[tx * 4 + 0][kk];
            c[1] += a * (double)Bs[tx * 4 + 1][kk];
            c[2] += a * (double)Bs[tx * 4 + 2][kk];
            c[3] += a * (double)Bs[tx * 4 + 3][kk];
        }
        __syncthreads();
    }
}

// ---------------- epilogues (register-only, 8-lane-group shuffles) ----------

__device__ void unimix_fin(const double* c, const float* bias, float* out,
                           int m0, int n0, int rowmul64, int t) {
    const int ty = threadIdx.x >> 3, tx = threadIdx.x & 7;
    double va[4];
#pragma unroll
    for (int q = 0; q < 4; q++) va[q] = c[q] + (double)bias[n0 + tx * 4 + q];
    double mx = fmax(fmax(va[0], va[1]), fmax(va[2], va[3]));
#pragma unroll
    for (int m = 1; m < 8; m <<= 1) mx = fmax(mx, __shfl_xor(mx, m));
    double sum = 0;
#pragma unroll
    for (int q = 0; q < 4; q++) sum += exp(va[q] - mx);
#pragma unroll
    for (int m = 1; m < 8; m <<= 1) sum += __shfl_xor(sum, m);
    double rinv = 1.0 / sum;
    long long row = rowmul64 ? ((long long)(m0 + ty) * 64 + t) : (long long)(m0 + ty);
    float4 o;
    float* po = (float*)&o;
#pragma unroll
    for (int q = 0; q < 4; q++)
        po[q] = (float)log(0.99 * (exp(va[q] - mx) * rinv) + 0.01 / 32.0);
    *(float4*)(out + row * 1024 + n0 + tx * 4) = o;
}

__device__ void sample_fin(const double* c, const P& p, int t, int m0, int n0) {
    const int ty = threadIdx.x >> 3, tx = threadIdx.x & 7;
    int b = m0 + ty;
    double va[4];
#pragma unroll
    for (int q = 0; q < 4; q++) va[q] = c[q] + (double)p.po_b2[n0 + tx * 4 + q];
    double mx = fmax(fmax(va[0], va[1]), fmax(va[2], va[3]));
#pragma unroll
    for (int m = 1; m < 8; m <<= 1) mx = fmax(mx, __shfl_xor(mx, m));
    double sum = 0;
#pragma unroll
    for (int q = 0; q < 4; q++) sum += exp(va[q] - mx);
#pragma unroll
    for (int m = 1; m < 8; m <<= 1) sum += __shfl_xor(sum, m);
    double rinv = 1.0 / sum;
    uint32_t ka, kb;
    step_key(t, ka, kb);
    float4 o;
    float* po = (float*)&o;
    double bv = -1e300; int bc = 0;
#pragma unroll
    for (int q = 0; q < 4; q++) {
        int cc = tx * 4 + q;
        double lp = log(0.99 * (exp(va[q] - mx) * rinv) + 0.01 / 32.0);
        po[q] = (float)lp;
        double val = gumbel_d((uint32_t)(b * 1024 + n0 + cc), ka, kb) + lp;
        if (val > bv) { bv = val; bc = cc; }
    }
#pragma unroll
    for (int m = 1; m < 8; m <<= 1) {
        double ov = __shfl_xor(bv, m);
        int oc = __shfl_xor(bc, m);
        if (ov > bv || (ov == bv && oc < bc)) { bv = ov; bc = oc; }
    }
    *(float4*)(p.out_posts + ((long long)b * 64 + t) * 1024 + n0 + tx * 4) = o;
    float4 oh;
    oh.x = (tx * 4 + 0 == bc) ? 1.0f : 0.0f;
    oh.y = (tx * 4 + 1 == bc) ? 1.0f : 0.0f;
    oh.z = (tx * 4 + 2 == bc) ? 1.0f : 0.0f;
    oh.w = (tx * 4 + 3 == bc) ? 1.0f : 0.0f;
    *(float4*)(p.out_states + ((long long)b * 64 + t) * 1536 + 512 + n0 + tx * 4) = oh;
    if (tx == 0) p.sidx[b * 32 + (n0 >> 5)] = bc;
}

// ---------------- the cooperative mega kernel -------------------------------

__global__ __launch_bounds__(NT, 2) void k_mega(P p) {
    __shared__ double As[32][17];
    __shared__ float  Bs[32][17];
    cg::grid_group grid = cg::this_grid();
    const int bid = blockIdx.x, tid = threadIdx.x;
    const int wid4 = bid * 4 + (tid >> 6);
    const int ty = tid >> 3, tx = tid & 7;
    double c[4];

    // ---- P0: WT transpose, zero deter, At0 rows for t=0 ----
    for (int i = bid * NT + tid; i < 1024 * 1536; i += NB * NT) {
        int cc = i / 1536, n = i % 1536;
        p.WT[(long long)cc * 1536 + n] = p.w_ih[(long long)n * 1536 + cc];
    }
    for (int i = bid * NT + tid; i < 512 * 512; i += NB * NT) p.deter[i] = 0.0;
    if (wid4 < 512)
        act_row(p.actions, p.aw, p.ab, p.ag, p.abt, p.At0 + (long long)wid4 * 512, wid4, 0);
    grid.sync();

    // ---- P1: 64 sequential steps ----
    for (int t = 0; t < 64; t++) {
        const double* At = (t & 1) ? p.At1 : p.At0;
        double* Atn = (t & 1) ? p.At0 : p.At1;

        // phase A: gh tiles (768) + gi tiles (768, one-hot gather) + act rows t+1
        for (int q = bid; q < 1664; q += NB) {
            if (q < 768) {
                int tm = q / 48, tn = q % 48;
                int m0 = tm * 32, n0 = tn * 32;
                run_tile_v(p.deter, 512, nullptr, 0, 512, p.w_hh, 512, 512, m0, n0, As, Bs, c);
#pragma unroll
                for (int j = 0; j < 4; j++)
                    p.gh[(long long)(m0 + ty) * 1536 + n0 + tx * 4 + j] =
                        c[j] + (double)p.b_hh[n0 + tx * 4 + j];
            } else if (q < 1536) {
                int q2 = q - 768;
                int tm = q2 / 48, tn = q2 % 48;
                int m0 = tm * 32, n0 = tn * 32;
                double g[4] = {0, 0, 0, 0};
                if (t > 0) {
                    int b = m0 + ty;
                    for (int s = 0; s < 32; s++) {
                        int cc = s * 32 + p.sidx[b * 32 + s];
                        const float4 v = *(const float4*)(p.WT + (long long)cc * 1536 + n0 + tx * 4);
                        g[0] += (double)v.x; g[1] += (double)v.y;
                        g[2] += (double)v.z; g[3] += (double)v.w;
                    }
                }
                run_tile_v(At, 512, nullptr, 0, 512, p.w_ih + 1024, 1536, 512, m0, n0, As, Bs, c);
#pragma unroll
                for (int j = 0; j < 4; j++)
                    p.gi[(long long)(m0 + ty) * 1536 + n0 + tx * 4 + j] =
                        c[j] + (double)p.b_ih[n0 + tx * 4 + j] + g[j];
            } else {
                if (t < 63) {
                    int rr = (q - 1536) * 4 + (tid >> 6);
                    act_row(p.actions, p.aw, p.ab, p.ag, p.abt,
                            Atn + (long long)rr * 512, rr, t + 1);
                }
            }
        }
        grid.sync();

        // phase B: GRU pointwise
        for (int e = bid * NT + tid; e < 512 * 512; e += NB * NT) {
            int b = e >> 9, d = e & 511;
            long long base = (long long)b * 1536;
            double ir = p.gi[base + d],          hr = p.gh[base + d];
            double iz = p.gi[base + 512 + d],    hz = p.gh[base + 512 + d];
            double in_ = p.gi[base + 1024 + d],  hn = p.gh[base + 1024 + d];
            double h = p.deter[e];
            double rr = 1.0 / (1.0 + exp(-(ir + hr)));
            double zz = 1.0 / (1.0 + exp(-(iz + hz)));
            double nn = tanh(in_ + rr * hn);
            double dn = (1.0 - zz) * nn + zz * h;
            p.deter[e] = dn;
            p.out_states[((long long)b * 64 + t) * 1536 + d] = (float)dn;
        }
        grid.sync();

        // phase C: posterior hidden (K=1024) [+ mode0 prior hidden]
        {
            int nq = p.mode1 ? 256 : 512;
            for (int q = bid; q < nq; q += NB) {
                if (q < 256) {
                    int tm = q >> 4, tn = q & 15;
                    int m0 = tm * 32, n0 = tn * 32;
                    run_tile_v(p.deter, 512, p.embeds + (long long)t * 512, 32768, 512,
                               p.po_w1, 1024, 1024, m0, n0, As, Bs, c);
#pragma unroll
                    for (int j = 0; j < 4; j++)
                        p.POraw[(long long)(m0 + ty) * 512 + n0 + tx * 4 + j] =
                            c[j] + (double)p.po_b1[n0 + tx * 4 + j];
                } else {
                    int q2 = q - 256;
                    int tm = q2 >> 4, tn = q2 & 15;
                    int m0 = tm * 32, n0 = tn * 32;
                    run_tile_v(p.deter, 512, nullptr, 0, 512, p.pr_w1, 512, 512, m0, n0, As, Bs, c);
#pragma unroll
                    for (int j = 0; j < 4; j++)
                        p.PRraw[(long long)(m0 + ty) * 512 + n0 + tx * 4 + j] =
                            c[j] + (double)p.pr_b1[n0 + tx * 4 + j];
                }
            }
        }
        grid.sync();

        // phase D: LN+mish rows
        {
            int nr = p.mode1 ? 512 : 1024;
            for (int r = wid4; r < nr; r += NB * 4) {
                if (r < 512) ln_row(p.POraw + (long long)r * 512, p.po_g, p.po_bt);
                else         ln_row(p.PRraw + (long long)(r - 512) * 512, p.pr_g, p.pr_bt);
            }
        }
        grid.sync();

        // phase E: posterior out + sample [+ mode0 prior out + unimix]
        {
            int nq = p.mode1 ? 512 : 1024;
            for (int q = bid; q < nq; q += NB) {
                if (q < 512) {
                    int tm = q >> 5, s = q & 31;
                    int m0 = tm * 32, n0 = s * 32;
                    run_tile_v(p.POraw, 512, nullptr, 0, 512, p.po_w2, 512, 512, m0, n0, As, Bs, c);
                    sample_fin(c, p, t, m0, n0);
                } else {
                    int q2 = q - 512;
                    int tm = q2 >> 5, s = q2 & 31;
                    int m0 = tm * 32, n0 = s * 32;
                    run_tile_v(p.PRraw, 512, nullptr, 0, 512, p.pr_w2, 512, 512, m0, n0, As, Bs, c);
                    unimix_fin(c, p.pr_b2, p.out_priors, m0, n0, 1, t);
                }
            }
        }
        grid.sync();
    }

    // ---- P2 (mode1): batched prior head from f32 states, rows m=(b*64+t) ----
    if (p.mode1) {
        for (int q = bid; q < 16384; q += NB) {
            int tm = q >> 4, tn = q & 15;
            int m0 = tm * 32, n0 = tn * 32;
            run_tile_v(nullptr, 0, p.out_states, 1536, 0, p.pr_w1, 512, 512, m0, n0, As, Bs, c);
#pragma unroll
            for (int j = 0; j < 4; j++)
                p.PH[(long long)(m0 + ty) * 512 + n0 + tx * 4 + j] =
                    (float)(c[j] + (double)p.pr_b1[n0 + tx * 4 + j]);
        }
        grid.sync();
        for (int r = wid4; r < 32768; r += NB * 4)
            ln_row_f32(p.PH + (long long)r * 512, p.pr_g, p.pr_bt);
        grid.sync();
        for (int q = bid; q < 32768; q += NB) {
            int tm = q >> 5, s = q & 31;
            int m0 = tm * 32, n0 = s * 32;
            run_tile_v(nullptr, 0, p.PH, 512, 0, p.pr_w2, 512, 512, m0, n0, As, Bs, c);
            unimix_fin(c, p.pr_b2, p.out_priors, m0, n0, 0, 0);
        }
    }
}

// ---------------- host -------------------------------------------------------

extern "C" void kernel_launch(void* const* d_in, const int* in_sizes, int n_in,
                              void* d_out, int out_size, void* d_ws, size_t ws_size,
                              hipStream_t stream) {
    P p;
    p.actions = (const float*)d_in[0];
    p.embeds  = (const float*)d_in[1];
    p.aw = (const float*)d_in[2];  p.ab = (const float*)d_in[3];
    p.ag = (const float*)d_in[4];  p.abt = (const float*)d_in[5];
    p.w_ih = (const float*)d_in[6]; p.w_hh = (const float*)d_in[7];
    p.b_ih = (const float*)d_in[8]; p.b_hh = (const float*)d_in[9];
    p.pr_w1 = (const float*)d_in[10]; p.pr_b1 = (const float*)d_in[11];
    p.pr_g = (const float*)d_in[12];  p.pr_bt = (const float*)d_in[13];
    p.pr_w2 = (const float*)d_in[14]; p.pr_b2 = (const float*)d_in[15];
    p.po_w1 = (const float*)d_in[16]; p.po_b1 = (const float*)d_in[17];
    p.po_g = (const float*)d_in[18];  p.po_bt = (const float*)d_in[19];
    p.po_w2 = (const float*)d_in[20]; p.po_b2 = (const float*)d_in[21];

    float* out = (float*)d_out;
    p.out_states = out;
    p.out_priors = out + (size_t)512 * 64 * 1536;
    p.out_posts  = out + (size_t)512 * 64 * 1536 + (size_t)512 * 64 * 1024;

    char* ws = (char*)d_ws;
    size_t off = 0;
    auto carve = [&](size_t bytes) -> char* {
        char* q = ws + off;
        off = (off + bytes + 255) & ~(size_t)255;
        return q;
    };
    p.sidx  = (int*)carve((size_t)512 * 32 * 4);
    p.WT    = (float*)carve((size_t)1024 * 1536 * 4);
    p.deter = (double*)carve((size_t)512 * 512 * 8);
    p.gh    = (double*)carve((size_t)512 * 1536 * 8);
    p.gi    = (double*)carve((size_t)512 * 1536 * 8);
    p.POraw = (double*)carve((size_t)512 * 512 * 8);
    p.PRraw = (double*)carve((size_t)512 * 512 * 8);
    p.At0   = (double*)carve((size_t)512 * 512 * 8);
    p.At1   = (double*)carve((size_t)512 * 512 * 8);
    size_t fixed = off;
    if (fixed > ws_size) return;  // fast visible failure
    p.PH = nullptr;
    p.mode1 = 0;
    if (fixed + (size_t)32768 * 512 * 4 <= ws_size) {
        p.PH = (float*)carve((size_t)32768 * 512 * 4);
        p.mode1 = 1;
    }

    void* args[] = { (void*)&p };
    hipLaunchCooperativeKernel((const void*)k_mega, dim3(NB), dim3(NT),
                               args, 0, stream);
}

// Round 9
// 39279.224 us; speedup vs baseline: 1.1285x; 1.1285x over previous
//
#include <hip/hip_runtime.h>
#include <hip/hip_cooperative_groups.h>
#include <stdint.h>

namespace cg = cooperative_groups;

typedef double double4_t __attribute__((ext_vector_type(4)));

#define NB 512
#define NT 256

struct P {
    const float *actions, *embeds, *aw, *ab, *ag, *abt;
    const float *w_ih, *w_hh, *b_ih, *b_hh;
    const float *pr_w1, *pr_b1, *pr_g, *pr_bt, *pr_w2, *pr_b2;
    const float *po_w1, *po_b1, *po_g, *po_bt, *po_w2, *po_b2;
    float *out_states, *out_priors, *out_posts;
    float *WT;          // [1024][1536] w_ih stoch-part transposed
    double *deter;      // [512][512]
    double *gh, *gi;    // [512][1536]
    double *POraw;      // [512][512]
    double *PRraw;      // [512][512] (mode0 only)
    double *At0, *At1;  // [512][512]
    float *PH;          // [32768][512] (mode1 only)
    int *sidx;          // [512*32]
    int *mfma_bad;      // HW self-test result
    int mode1;
};

// ---------------- math helpers (f64) ---------------------------------------

__device__ __forceinline__ double mish_d(double x) {
    double sp = fmax(x, 0.0) + log1p(exp(-fabs(x)));
    return x * tanh(sp);
}

// ---------------- threefry2x32 (JAX partitionable semantics) ----------------

__device__ __forceinline__ uint32_t rotl32(uint32_t v, int r) {
    return (v << r) | (v >> (32 - r));
}

__device__ __forceinline__ void tf2x32(uint32_t k0, uint32_t k1, uint32_t& x0, uint32_t& x1) {
    const uint32_t ks2 = k0 ^ k1 ^ 0x1BD11BDAu;
    const int ra[4] = {13, 15, 26, 6};
    const int rb[4] = {17, 29, 16, 24};
    x0 += k0; x1 += k1;
#pragma unroll
    for (int i = 0; i < 4; i++) { x0 += x1; x1 = rotl32(x1, ra[i]); x1 ^= x0; }
    x0 += k1; x1 += ks2 + 1u;
#pragma unroll
    for (int i = 0; i < 4; i++) { x0 += x1; x1 = rotl32(x1, rb[i]); x1 ^= x0; }
    x0 += ks2; x1 += k0 + 2u;
#pragma unroll
    for (int i = 0; i < 4; i++) { x0 += x1; x1 = rotl32(x1, ra[i]); x1 ^= x0; }
    x0 += k0; x1 += k1 + 3u;
#pragma unroll
    for (int i = 0; i < 4; i++) { x0 += x1; x1 = rotl32(x1, rb[i]); x1 ^= x0; }
    x0 += k1; x1 += ks2 + 4u;
#pragma unroll
    for (int i = 0; i < 4; i++) { x0 += x1; x1 = rotl32(x1, ra[i]); x1 ^= x0; }
    x0 += ks2; x1 += k0 + 5u;
}

__device__ __forceinline__ void step_key(int t, uint32_t& ka, uint32_t& kb) {
    uint32_t x0 = 0u, x1 = (uint32_t)t;
    tf2x32(0u, 42u, x0, x1);
    ka = x0; kb = x1;
}

__device__ __forceinline__ double gumbel_d(uint32_t n, uint32_t ka, uint32_t kb) {
    uint32_t x0 = 0u, x1 = n;
    tf2x32(ka, kb, x0, x1);
    uint32_t bits = x0 ^ x1;
    uint32_t fb = (bits >> 9) | 0x3f800000u;
    float f = __uint_as_float(fb) - 1.0f;
    double u = fmax((double)f, 1.17549435e-38);
    return -log(-log(u));
}

// ---------------- per-wave row ops ------------------------------------------

__device__ void act_row(const float* actions, const float* aw, const float* ab,
                        const float* ag, const float* abt, double* dst, int b, int t) {
    int l = threadIdx.x & 63;
    double x[8];
    double s = 0;
#pragma unroll
    for (int i = 0; i < 8; i++) {
        int h = l + 64 * i;
        double a = (double)ab[h];
        if (t > 0) {
            const float* ac = actions + ((long long)b * 64 + (t - 1)) * 32;
            #pragma unroll 4
            for (int k = 0; k < 32; k++)
                a += (double)ac[k] * (double)aw[h * 32 + k];
        }
        x[i] = a; s += a;
    }
#pragma unroll
    for (int m = 1; m < 64; m <<= 1) s += __shfl_xor(s, m);
    double mean = s * (1.0 / 512.0);
    double vv = 0;
#pragma unroll
    for (int i = 0; i < 8; i++) { double d = x[i] - mean; vv += d * d; }
#pragma unroll
    for (int m = 1; m < 64; m <<= 1) vv += __shfl_xor(vv, m);
    double inv = 1.0 / sqrt(vv * (1.0 / 512.0) + 1e-5);
#pragma unroll
    for (int i = 0; i < 8; i++) {
        int h = l + 64 * i;
        dst[h] = mish_d((x[i] - mean) * inv * (double)ag[h] + (double)abt[h]);
    }
}

__device__ void ln_row(double* row, const float* g, const float* bt) {
    int l = threadIdx.x & 63;
    double x[8];
    double s = 0;
#pragma unroll
    for (int i = 0; i < 8; i++) { x[i] = row[l + 64 * i]; s += x[i]; }
#pragma unroll
    for (int m = 1; m < 64; m <<= 1) s += __shfl_xor(s, m);
    double mean = s * (1.0 / 512.0);
    double vv = 0;
#pragma unroll
    for (int i = 0; i < 8; i++) { double d = x[i] - mean; vv += d * d; }
#pragma unroll
    for (int m = 1; m < 64; m <<= 1) vv += __shfl_xor(vv, m);
    double inv = 1.0 / sqrt(vv * (1.0 / 512.0) + 1e-5);
#pragma unroll
    for (int i = 0; i < 8; i++) {
        int h = l + 64 * i;
        row[h] = mish_d((x[i] - mean) * inv * (double)g[h] + (double)bt[h]);
    }
}

__device__ void ln_row_f32(float* row, const float* g, const float* bt) {
    int l = threadIdx.x & 63;
    double x[8];
    double s = 0;
#pragma unroll
    for (int i = 0; i < 8; i++) { x[i] = (double)row[l + 64 * i]; s += x[i]; }
#pragma unroll
    for (int m = 1; m < 64; m <<= 1) s += __shfl_xor(s, m);
    double mean = s * (1.0 / 512.0);
    double vv = 0;
#pragma unroll
    for (int i = 0; i < 8; i++) { double d = x[i] - mean; vv += d * d; }
#pragma unroll
    for (int m = 1; m < 64; m <<= 1) vv += __shfl_xor(vv, m);
    double inv = 1.0 / sqrt(vv * (1.0 / 512.0) + 1e-5);
#pragma unroll
    for (int i = 0; i < 8; i++) {
        int h = l + 64 * i;
        row[h] = (float)mish_d((x[i] - mean) * inv * (double)g[h] + (double)bt[h]);
    }
}

// ---------------- 32x32 tile, dbuf K=32 slices, MFMA with vector fallback ---
// C[m][n] = sum_k A[m][k]*B[n][k]. A: k<asplit from Ad (f64), else Af (f32).
// Result: thread (ty=tid>>3, tx=tid&7) holds c[j] = C[m0+ty][n0+tx*4+j].

__device__ void run_tile(const double* Ad, long long ldad,
                         const float* Af, long long ldaf, int asplit,
                         const float* Bp, long long ldb, int K,
                         int m0, int n0,
                         double (&As)[2][32][33], float (&Bs)[2][32][33],
                         double (&sm)[32][33], int use_mfma, double* c) {
    const int tid = threadIdx.x;
    const int ty = tid >> 3, tx = tid & 7;
    const int sr = tid >> 3, sk = (tid & 7) * 4;
    const int w = tid >> 6, l = tid & 63, l15 = l & 15, l16 = l >> 4;
    double ra[4]; float rb[4];
#pragma unroll
    for (int i = 0; i < 4; i++) {
        int k = sk + i;
        ra[i] = (k < asplit) ? Ad[(long long)(m0 + sr) * ldad + k]
                             : (double)Af[(long long)(m0 + sr) * ldaf + (k - asplit)];
        rb[i] = Bp[(long long)(n0 + sr) * ldb + k];
    }
#pragma unroll
    for (int i = 0; i < 4; i++) { As[0][sr][sk + i] = ra[i]; Bs[0][sr][sk + i] = rb[i]; }
    __syncthreads();
    double4_t acc = {0.0, 0.0, 0.0, 0.0};
    c[0] = c[1] = c[2] = c[3] = 0.0;
    const int nkb = K >> 5;
    int cur = 0;
    for (int kb = 0; kb < nkb; kb++) {
        if (kb + 1 < nkb) {
            int k0 = (kb + 1) << 5;
#pragma unroll
            for (int i = 0; i < 4; i++) {
                int k = k0 + sk + i;
                ra[i] = (k < asplit) ? Ad[(long long)(m0 + sr) * ldad + k]
                                     : (double)Af[(long long)(m0 + sr) * ldaf + (k - asplit)];
                rb[i] = Bp[(long long)(n0 + sr) * ldb + k];
            }
        }
        if (use_mfma) {
#pragma unroll
            for (int ks = 0; ks < 8; ks++) {
                double a = As[cur][(w >> 1) * 16 + l15][ks * 4 + l16];
                double b = (double)Bs[cur][(w & 1) * 16 + l15][ks * 4 + l16];
                acc = __builtin_amdgcn_mfma_f64_16x16x4f64(a, b, acc, 0, 0, 0);
            }
        } else {
#pragma unroll 8
            for (int kk = 0; kk < 32; kk++) {
                double a = As[cur][ty][kk];
                c[0] += a * (double)Bs[cur][tx * 4 + 0][kk];
                c[1] += a * (double)Bs[cur][tx * 4 + 1][kk];
                c[2] += a * (double)Bs[cur][tx * 4 + 2][kk];
                c[3] += a * (double)Bs[cur][tx * 4 + 3][kk];
            }
        }
        if (kb + 1 < nkb) {
            int nx = cur ^ 1;
#pragma unroll
            for (int i = 0; i < 4; i++) { As[nx][sr][sk + i] = ra[i]; Bs[nx][sr][sk + i] = rb[i]; }
        }
        __syncthreads();
        cur ^= 1;
    }
    if (use_mfma) {
        // D layout: col=lane&15, row=(lane>>4)*4+v within the wave's 16x16 quadrant
        int rl = (w >> 1) * 16 + l16 * 4, nl = (w & 1) * 16 + l15;
#pragma unroll
        for (int v = 0; v < 4; v++) sm[rl + v][nl] = acc[v];
        __syncthreads();
#pragma unroll
        for (int j = 0; j < 4; j++) c[j] = sm[ty][tx * 4 + j];
        __syncthreads();
    }
}

// ---------------- epilogues (register-only, 8-lane-group shuffles) ----------

__device__ void unimix_fin(const double* c, const float* bias, float* out,
                           int m0, int n0, int rowmul64, int t) {
    const int ty = threadIdx.x >> 3, tx = threadIdx.x & 7;
    double va[4];
#pragma unroll
    for (int q = 0; q < 4; q++) va[q] = c[q] + (double)bias[n0 + tx * 4 + q];
    double mx = fmax(fmax(va[0], va[1]), fmax(va[2], va[3]));
#pragma unroll
    for (int m = 1; m < 8; m <<= 1) mx = fmax(mx, __shfl_xor(mx, m));
    double sum = 0;
#pragma unroll
    for (int q = 0; q < 4; q++) sum += exp(va[q] - mx);
#pragma unroll
    for (int m = 1; m < 8; m <<= 1) sum += __shfl_xor(sum, m);
    double rinv = 1.0 / sum;
    long long row = rowmul64 ? ((long long)(m0 + ty) * 64 + t) : (long long)(m0 + ty);
    float4 o;
    float* po = (float*)&o;
#pragma unroll
    for (int q = 0; q < 4; q++)
        po[q] = (float)log(0.99 * (exp(va[q] - mx) * rinv) + 0.01 / 32.0);
    *(float4*)(out + row * 1024 + n0 + tx * 4) = o;
}

__device__ void sample_fin(const double* c, const P& p, int t, int m0, int n0) {
    const int ty = threadIdx.x >> 3, tx = threadIdx.x & 7;
    int b = m0 + ty;
    double va[4];
#pragma unroll
    for (int q = 0; q < 4; q++) va[q] = c[q] + (double)p.po_b2[n0 + tx * 4 + q];
    double mx = fmax(fmax(va[0], va[1]), fmax(va[2], va[3]));
#pragma unroll
    for (int m = 1; m < 8; m <<= 1) mx = fmax(mx, __shfl_xor(mx, m));
    double sum = 0;
#pragma unroll
    for (int q = 0; q < 4; q++) sum += exp(va[q] - mx);
#pragma unroll
    for (int m = 1; m < 8; m <<= 1) sum += __shfl_xor(sum, m);
    double rinv = 1.0 / sum;
    uint32_t ka, kb;
    step_key(t, ka, kb);
    float4 o;
    float* po = (float*)&o;
    double bv = -1e300; int bc = 0;
#pragma unroll
    for (int q = 0; q < 4; q++) {
        int cc = tx * 4 + q;
        double lp = log(0.99 * (exp(va[q] - mx) * rinv) + 0.01 / 32.0);
        po[q] = (float)lp;
        double val = gumbel_d((uint32_t)(b * 1024 + n0 + cc), ka, kb) + lp;
        if (val > bv) { bv = val; bc = cc; }
    }
#pragma unroll
    for (int m = 1; m < 8; m <<= 1) {
        double ov = __shfl_xor(bv, m);
        int oc = __shfl_xor(bc, m);
        if (ov > bv || (ov == bv && oc < bc)) { bv = ov; bc = oc; }
    }
    *(float4*)(p.out_posts + ((long long)b * 64 + t) * 1024 + n0 + tx * 4) = o;
    float4 oh;
    oh.x = (tx * 4 + 0 == bc) ? 1.0f : 0.0f;
    oh.y = (tx * 4 + 1 == bc) ? 1.0f : 0.0f;
    oh.z = (tx * 4 + 2 == bc) ? 1.0f : 0.0f;
    oh.w = (tx * 4 + 3 == bc) ? 1.0f : 0.0f;
    *(float4*)(p.out_states + ((long long)b * 64 + t) * 1536 + 512 + n0 + tx * 4) = oh;
    if (tx == 0) p.sidx[b * 32 + (n0 >> 5)] = bc;
}

// ---------------- the cooperative mega kernel -------------------------------

__global__ __launch_bounds__(NT, 2) void k_mega(P p) {
    __shared__ double As[2][32][33];
    __shared__ float  Bs[2][32][33];
    __shared__ double sm[32][33];
    cg::grid_group grid = cg::this_grid();
    const int bid = blockIdx.x, tid = threadIdx.x;
    const int wid4 = bid * 4 + (tid >> 6);
    const int ty = tid >> 3, tx = tid & 7;
    double c[4];

    // ---- P0: WT transpose, zero deter, At0 rows for t=0, MFMA self-test ----
    for (int i = bid * NT + tid; i < 1024 * 1536; i += NB * NT) {
        int cc = i / 1536, n = i % 1536;
        p.WT[(long long)cc * 1536 + n] = p.w_ih[(long long)n * 1536 + cc];
    }
    for (int i = bid * NT + tid; i < 512 * 512; i += NB * NT) p.deter[i] = 0.0;
    if (wid4 < 512)
        act_row(p.actions, p.aw, p.ab, p.ag, p.abt, p.At0 + (long long)wid4 * 512, wid4, 0);
    if (bid == 0) {
        __shared__ int stbad;
        if (tid == 0) stbad = 0;
        __syncthreads();
        if (tid < 64) {
            int l15 = tid & 15, l16 = tid >> 4;
            // A[m][k]=m*4+k+1 (m=l15,k=l16); B[n][k]=3n-2k+5 (n=l15,k=l16) — asymmetric
            double a = (double)(l15 * 4 + l16 + 1);
            double b = (double)(3 * l15 - 2 * l16 + 5);
            double4_t tacc = {0.0, 0.0, 0.0, 0.0};
            tacc = __builtin_amdgcn_mfma_f64_16x16x4f64(a, b, tacc, 0, 0, 0);
            int bad = 0;
#pragma unroll
            for (int v = 0; v < 4; v++) {
                int m = l16 * 4 + v, n = l15;
                double ref = 0;
                for (int k = 0; k < 4; k++) ref += (double)((m * 4 + k + 1) * (3 * n - 2 * k + 5));
                if (tacc[v] != ref) bad = 1;
            }
            if (bad) atomicOr(&stbad, 1);
        }
        __syncthreads();
        if (tid == 0) { *p.mfma_bad = stbad; __threadfence(); }
    }
    grid.sync();
    const int use_mfma = (*(volatile int*)p.mfma_bad) == 0 ? 1 : 0;

    // ---- P1: 64 sequential steps ----
    for (int t = 0; t < 64; t++) {
        const double* At = (t & 1) ? p.At1 : p.At0;
        double* Atn = (t & 1) ? p.At0 : p.At1;

        // phase A: gh tiles (768) + gi tiles (768, one-hot gather) + act rows t+1
        for (int q = bid; q < 1664; q += NB) {
            if (q < 768) {
                int tm = q / 48, tn = q % 48;
                int m0 = tm * 32, n0 = tn * 32;
                run_tile(p.deter, 512, nullptr, 0, 512, p.w_hh, 512, 512, m0, n0,
                         As, Bs, sm, use_mfma, c);
#pragma unroll
                for (int j = 0; j < 4; j++)
                    p.gh[(long long)(m0 + ty) * 1536 + n0 + tx * 4 + j] =
                        c[j] + (double)p.b_hh[n0 + tx * 4 + j];
            } else if (q < 1536) {
                int q2 = q - 768;
                int tm = q2 / 48, tn = q2 % 48;
                int m0 = tm * 32, n0 = tn * 32;
                double g[4] = {0, 0, 0, 0};
                if (t > 0) {
                    int b = m0 + ty;
                    for (int s = 0; s < 32; s++) {
                        int cc = s * 32 + p.sidx[b * 32 + s];
                        const float4 v = *(const float4*)(p.WT + (long long)cc * 1536 + n0 + tx * 4);
                        g[0] += (double)v.x; g[1] += (double)v.y;
                        g[2] += (double)v.z; g[3] += (double)v.w;
                    }
                }
                run_tile(At, 512, nullptr, 0, 512, p.w_ih + 1024, 1536, 512, m0, n0,
                         As, Bs, sm, use_mfma, c);
#pragma unroll
                for (int j = 0; j < 4; j++)
                    p.gi[(long long)(m0 + ty) * 1536 + n0 + tx * 4 + j] =
                        c[j] + (double)p.b_ih[n0 + tx * 4 + j] + g[j];
            } else {
                if (t < 63) {
                    int rr = (q - 1536) * 4 + (tid >> 6);
                    act_row(p.actions, p.aw, p.ab, p.ag, p.abt,
                            Atn + (long long)rr * 512, rr, t + 1);
                }
            }
        }
        grid.sync();

        // phase B: GRU pointwise
        for (int e = bid * NT + tid; e < 512 * 512; e += NB * NT) {
            int b = e >> 9, d = e & 511;
            long long base = (long long)b * 1536;
            double ir = p.gi[base + d],          hr = p.gh[base + d];
            double iz = p.gi[base + 512 + d],    hz = p.gh[base + 512 + d];
            double in_ = p.gi[base + 1024 + d],  hn = p.gh[base + 1024 + d];
            double h = p.deter[e];
            double rr = 1.0 / (1.0 + exp(-(ir + hr)));
            double zz = 1.0 / (1.0 + exp(-(iz + hz)));
            double nn = tanh(in_ + rr * hn);
            double dn = (1.0 - zz) * nn + zz * h;
            p.deter[e] = dn;
            p.out_states[((long long)b * 64 + t) * 1536 + d] = (float)dn;
        }
        grid.sync();

        // phase C: posterior hidden (K=1024) [+ mode0 prior hidden]
        {
            int nq = p.mode1 ? 256 : 512;
            for (int q = bid; q < nq; q += NB) {
                if (q < 256) {
                    int tm = q >> 4, tn = q & 15;
                    int m0 = tm * 32, n0 = tn * 32;
                    run_tile(p.deter, 512, p.embeds + (long long)t * 512, 32768, 512,
                             p.po_w1, 1024, 1024, m0, n0, As, Bs, sm, use_mfma, c);
#pragma unroll
                    for (int j = 0; j < 4; j++)
                        p.POraw[(long long)(m0 + ty) * 512 + n0 + tx * 4 + j] =
                            c[j] + (double)p.po_b1[n0 + tx * 4 + j];
                } else {
                    int q2 = q - 256;
                    int tm = q2 >> 4, tn = q2 & 15;
                    int m0 = tm * 32, n0 = tn * 32;
                    run_tile(p.deter, 512, nullptr, 0, 512, p.pr_w1, 512, 512, m0, n0,
                             As, Bs, sm, use_mfma, c);
#pragma unroll
                    for (int j = 0; j < 4; j++)
                        p.PRraw[(long long)(m0 + ty) * 512 + n0 + tx * 4 + j] =
                            c[j] + (double)p.pr_b1[n0 + tx * 4 + j];
                }
            }
        }
        grid.sync();

        // phase D: LN+mish rows
        {
            int nr = p.mode1 ? 512 : 1024;
            for (int r = wid4; r < nr; r += NB * 4) {
                if (r < 512) ln_row(p.POraw + (long long)r * 512, p.po_g, p.po_bt);
                else         ln_row(p.PRraw + (long long)(r - 512) * 512, p.pr_g, p.pr_bt);
            }
        }
        grid.sync();

        // phase E: posterior out + sample [+ mode0 prior out + unimix]
        {
            int nq = p.mode1 ? 512 : 1024;
            for (int q = bid; q < nq; q += NB) {
                if (q < 512) {
                    int tm = q >> 5, s = q & 31;
                    int m0 = tm * 32, n0 = s * 32;
                    run_tile(p.POraw, 512, nullptr, 0, 512, p.po_w2, 512, 512, m0, n0,
                             As, Bs, sm, use_mfma, c);
                    sample_fin(c, p, t, m0, n0);
                } else {
                    int q2 = q - 512;
                    int tm = q2 >> 5, s = q2 & 31;
                    int m0 = tm * 32, n0 = s * 32;
                    run_tile(p.PRraw, 512, nullptr, 0, 512, p.pr_w2, 512, 512, m0, n0,
                             As, Bs, sm, use_mfma, c);
                    unimix_fin(c, p.pr_b2, p.out_priors, m0, n0, 1, t);
                }
            }
        }
        grid.sync();
    }

    // ---- P2 (mode1): batched prior head from f32 states, rows m=(b*64+t) ----
    if (p.mode1) {
        for (int q = bid; q < 16384; q += NB) {
            int tm = q >> 4, tn = q & 15;
            int m0 = tm * 32, n0 = tn * 32;
            run_tile(nullptr, 0, p.out_states, 1536, 0, p.pr_w1, 512, 512, m0, n0,
                     As, Bs, sm, use_mfma, c);
#pragma unroll
            for (int j = 0; j < 4; j++)
                p.PH[(long long)(m0 + ty) * 512 + n0 + tx * 4 + j] =
                    (float)(c[j] + (double)p.pr_b1[n0 + tx * 4 + j]);
        }
        grid.sync();
        for (int r = wid4; r < 32768; r += NB * 4)
            ln_row_f32(p.PH + (long long)r * 512, p.pr_g, p.pr_bt);
        grid.sync();
        for (int q = bid; q < 32768; q += NB) {
            int tm = q >> 5, s = q & 31;
            int m0 = tm * 32, n0 = s * 32;
            run_tile(nullptr, 0, p.PH, 512, 0, p.pr_w2, 512, 512, m0, n0,
                     As, Bs, sm, use_mfma, c);
            unimix_fin(c, p.pr_b2, p.out_priors, m0, n0, 0, 0);
        }
    }
}

// ---------------- host -------------------------------------------------------

extern "C" void kernel_launch(void* const* d_in, const int* in_sizes, int n_in,
                              void* d_out, int out_size, void* d_ws, size_t ws_size,
                              hipStream_t stream) {
    P p;
    p.actions = (const float*)d_in[0];
    p.embeds  = (const float*)d_in[1];
    p.aw = (const float*)d_in[2];  p.ab = (const float*)d_in[3];
    p.ag = (const float*)d_in[4];  p.abt = (const float*)d_in[5];
    p.w_ih = (const float*)d_in[6]; p.w_hh = (const float*)d_in[7];
    p.b_ih = (const float*)d_in[8]; p.b_hh = (const float*)d_in[9];
    p.pr_w1 = (const float*)d_in[10]; p.pr_b1 = (const float*)d_in[11];
    p.pr_g = (const float*)d_in[12];  p.pr_bt = (const float*)d_in[13];
    p.pr_w2 = (const float*)d_in[14]; p.pr_b2 = (const float*)d_in[15];
    p.po_w1 = (const float*)d_in[16]; p.po_b1 = (const float*)d_in[17];
    p.po_g = (const float*)d_in[18];  p.po_bt = (const float*)d_in[19];
    p.po_w2 = (const float*)d_in[20]; p.po_b2 = (const float*)d_in[21];

    float* out = (float*)d_out;
    p.out_states = out;
    p.out_priors = out + (size_t)512 * 64 * 1536;
    p.out_posts  = out + (size_t)512 * 64 * 1536 + (size_t)512 * 64 * 1024;

    char* ws = (char*)d_ws;
    size_t off = 0;
    auto carve = [&](size_t bytes) -> char* {
        char* q = ws + off;
        off = (off + bytes + 255) & ~(size_t)255;
        return q;
    };
    p.mfma_bad = (int*)carve(256);
    p.sidx  = (int*)carve((size_t)512 * 32 * 4);
    p.WT    = (float*)carve((size_t)1024 * 1536 * 4);
    p.deter = (double*)carve((size_t)512 * 512 * 8);
    p.gh    = (double*)carve((size_t)512 * 1536 * 8);
    p.gi    = (double*)carve((size_t)512 * 1536 * 8);
    p.POraw = (double*)carve((size_t)512 * 512 * 8);
    p.PRraw = (double*)carve((size_t)512 * 512 * 8);
    p.At0   = (double*)carve((size_t)512 * 512 * 8);
    p.At1   = (double*)carve((size_t)512 * 512 * 8);
    size_t fixed = off;
    if (fixed > ws_size) return;  // fast visible failure
    p.PH = nullptr;
    p.mode1 = 0;
    if (fixed + (size_t)32768 * 512 * 4 <= ws_size) {
        p.PH = (float*)carve((size_t)32768 * 512 * 4);
        p.mode1 = 1;
    }

    void* args[] = { (void*)&p };
    hipLaunchCooperativeKernel((const void*)k_mega, dim3(NB), dim3(NT),
                               args, 0, stream);
}

// Round 11
// 37397.498 us; speedup vs baseline: 1.1852x; 1.0503x over previous
//
#include <hip/hip_runtime.h>
#include <hip/hip_cooperative_groups.h>
#include <stdint.h>

namespace cg = cooperative_groups;

#define NT 256

struct P {
    const float *actions, *embeds, *aw, *ab, *ag, *abt;
    const float *w_ih, *w_hh, *b_ih, *b_hh;
    const float *pr_w1, *pr_b1, *pr_g, *pr_bt, *pr_w2, *pr_b2;
    const float *po_w1, *po_b1, *po_g, *po_bt, *po_w2, *po_b2;
    float *out_states, *out_priors, *out_posts;
    float *WT;          // [1024][1536] w_ih stoch-part transposed
    double *deter;      // [512][512]
    double *gh, *gi;    // [512][1536]
    double *POraw;      // [512][512]
    double *PRraw;      // [512][512]
    double *At0, *At1;  // [512][512]
    int *sidx;          // [512*32]
};

// ---------------- math helpers (f64) ---------------------------------------

__device__ __forceinline__ double mish_d(double x) {
    double sp = fmax(x, 0.0) + log1p(exp(-fabs(x)));
    return x * tanh(sp);
}

// ---------------- threefry2x32 (JAX partitionable semantics) ----------------

__device__ __forceinline__ uint32_t rotl32(uint32_t v, int r) {
    return (v << r) | (v >> (32 - r));
}

__device__ __forceinline__ void tf2x32(uint32_t k0, uint32_t k1, uint32_t& x0, uint32_t& x1) {
    const uint32_t ks2 = k0 ^ k1 ^ 0x1BD11BDAu;
    const int ra[4] = {13, 15, 26, 6};
    const int rb[4] = {17, 29, 16, 24};
    x0 += k0; x1 += k1;
#pragma unroll
    for (int i = 0; i < 4; i++) { x0 += x1; x1 = rotl32(x1, ra[i]); x1 ^= x0; }
    x0 += k1; x1 += ks2 + 1u;
#pragma unroll
    for (int i = 0; i < 4; i++) { x0 += x1; x1 = rotl32(x1, rb[i]); x1 ^= x0; }
    x0 += ks2; x1 += k0 + 2u;
#pragma unroll
    for (int i = 0; i < 4; i++) { x0 += x1; x1 = rotl32(x1, ra[i]); x1 ^= x0; }
    x0 += k0; x1 += k1 + 3u;
#pragma unroll
    for (int i = 0; i < 4; i++) { x0 += x1; x1 = rotl32(x1, rb[i]); x1 ^= x0; }
    x0 += k1; x1 += ks2 + 4u;
#pragma unroll
    for (int i = 0; i < 4; i++) { x0 += x1; x1 = rotl32(x1, ra[i]); x1 ^= x0; }
    x0 += ks2; x1 += k0 + 5u;
}

__device__ __forceinline__ void step_key(int t, uint32_t& ka, uint32_t& kb) {
    uint32_t x0 = 0u, x1 = (uint32_t)t;
    tf2x32(0u, 42u, x0, x1);
    ka = x0; kb = x1;
}

__device__ __forceinline__ double gumbel_d(uint32_t n, uint32_t ka, uint32_t kb) {
    uint32_t x0 = 0u, x1 = n;
    tf2x32(ka, kb, x0, x1);
    uint32_t bits = x0 ^ x1;
    uint32_t fb = (bits >> 9) | 0x3f800000u;
    float f = __uint_as_float(fb) - 1.0f;
    double u = fmax((double)f, 1.17549435e-38);
    return -log(-log(u));
}

// ---------------- per-wave row ops ------------------------------------------

__device__ void act_row(const float* actions, const float* aw, const float* ab,
                        const float* ag, const float* abt, double* dst, int b, int t) {
    int l = threadIdx.x & 63;
    double x[8];
    double s = 0;
#pragma unroll
    for (int i = 0; i < 8; i++) {
        int h = l + 64 * i;
        double a = (double)ab[h];
        if (t > 0) {
            const float* ac = actions + ((long long)b * 64 + (t - 1)) * 32;
            #pragma unroll 4
            for (int k = 0; k < 32; k++)
                a += (double)ac[k] * (double)aw[h * 32 + k];
        }
        x[i] = a; s += a;
    }
#pragma unroll
    for (int m = 1; m < 64; m <<= 1) s += __shfl_xor(s, m);
    double mean = s * (1.0 / 512.0);
    double vv = 0;
#pragma unroll
    for (int i = 0; i < 8; i++) { double d = x[i] - mean; vv += d * d; }
#pragma unroll
    for (int m = 1; m < 64; m <<= 1) vv += __shfl_xor(vv, m);
    double inv = 1.0 / sqrt(vv * (1.0 / 512.0) + 1e-5);
#pragma unroll
    for (int i = 0; i < 8; i++) {
        int h = l + 64 * i;
        dst[h] = mish_d((x[i] - mean) * inv * (double)ag[h] + (double)abt[h]);
    }
}

__device__ void ln_row(double* row, const float* g, const float* bt) {
    int l = threadIdx.x & 63;
    double x[8];
    double s = 0;
#pragma unroll
    for (int i = 0; i < 8; i++) { x[i] = row[l + 64 * i]; s += x[i]; }
#pragma unroll
    for (int m = 1; m < 64; m <<= 1) s += __shfl_xor(s, m);
    double mean = s * (1.0 / 512.0);
    double vv = 0;
#pragma unroll
    for (int i = 0; i < 8; i++) { double d = x[i] - mean; vv += d * d; }
#pragma unroll
    for (int m = 1; m < 64; m <<= 1) vv += __shfl_xor(vv, m);
    double inv = 1.0 / sqrt(vv * (1.0 / 512.0) + 1e-5);
#pragma unroll
    for (int i = 0; i < 8; i++) {
        int h = l + 64 * i;
        row[h] = mish_d((x[i] - mean) * inv * (double)g[h] + (double)bt[h]);
    }
}

// ---------------- 64x64 tile, K=512, dbuf slice=16 (vector f64) -------------
// C[m][n] = sum_k A[m][k]*B[n][k]; thread (ty=tid>>4, tx=tid&15) owns
// rows m0+ty*4+i, cols n0+tx*4+j -> c[i][j].  LDS: As/Bs [2][64][17].

__device__ void tile64(const double* __restrict__ Ad, long long lda,
                       const float* __restrict__ Bp, long long ldb,
                       int m0, int n0,
                       double (&As)[2][64][17], float (&Bs)[2][64][17],
                       double (&c)[4][4]) {
    const int tid = threadIdx.x;
    const int ty = tid >> 4, tx = tid & 15;
    const int sr = tid >> 2, sk = (tid & 3) * 4;
#pragma unroll
    for (int i = 0; i < 4; i++)
#pragma unroll
        for (int j = 0; j < 4; j++) c[i][j] = 0.0;
    double ra[4]; float rb[4];
#pragma unroll
    for (int i = 0; i < 4; i++) {
        ra[i] = Ad[(long long)(m0 + sr) * lda + sk + i];
        rb[i] = Bp[(long long)(n0 + sr) * ldb + sk + i];
    }
#pragma unroll
    for (int i = 0; i < 4; i++) { As[0][sr][sk + i] = ra[i]; Bs[0][sr][sk + i] = rb[i]; }
    __syncthreads();
    int cur = 0;
    for (int kb = 0; kb < 32; kb++) {
        if (kb < 31) {
            int k0 = (kb + 1) * 16;
#pragma unroll
            for (int i = 0; i < 4; i++) {
                ra[i] = Ad[(long long)(m0 + sr) * lda + k0 + sk + i];
                rb[i] = Bp[(long long)(n0 + sr) * ldb + k0 + sk + i];
            }
        }
#pragma unroll
        for (int kk = 0; kk < 16; kk++) {
            double av[4], bv[4];
#pragma unroll
            for (int i = 0; i < 4; i++) av[i] = As[cur][ty * 4 + i][kk];
#pragma unroll
            for (int j = 0; j < 4; j++) bv[j] = (double)Bs[cur][tx * 4 + j][kk];
#pragma unroll
            for (int i = 0; i < 4; i++)
#pragma unroll
                for (int j = 0; j < 4; j++) c[i][j] = fma(av[i], bv[j], c[i][j]);
        }
        if (kb < 31) {
            int nx = cur ^ 1;
#pragma unroll
            for (int i = 0; i < 4; i++) { As[nx][sr][sk + i] = ra[i]; Bs[nx][sr][sk + i] = rb[i]; }
        }
        __syncthreads();
        cur ^= 1;
    }
}

// ---------------- 32x32 tile, generic K, dbuf slice=16 (vector f64) ---------
// A: k<asplit from Ad (f64), else Af (f32). thread (ty=tid>>3, tx=tid&7)
// owns row m0+ty, cols n0+tx*4..+3 -> c[4].

__device__ void tile32(const double* Ad, long long ldad,
                       const float* Af, long long ldaf, int asplit,
                       const float* Bp, long long ldb, int K,
                       int m0, int n0,
                       double (&As)[2][64][17], float (&Bs)[2][64][17],
                       double* c) {
    const int tid = threadIdx.x;
    const int ty = tid >> 3, tx = tid & 7;
    const int sr = tid >> 3, sk = (tid & 7) * 2;
    double ra[2]; float rb[2];
#pragma unroll
    for (int i = 0; i < 2; i++) {
        int k = sk + i;
        ra[i] = (k < asplit) ? Ad[(long long)(m0 + sr) * ldad + k]
                             : (double)Af[(long long)(m0 + sr) * ldaf + (k - asplit)];
        rb[i] = Bp[(long long)(n0 + sr) * ldb + k];
    }
#pragma unroll
    for (int i = 0; i < 2; i++) { As[0][sr][sk + i] = ra[i]; Bs[0][sr][sk + i] = rb[i]; }
    __syncthreads();
    c[0] = c[1] = c[2] = c[3] = 0.0;
    const int nkb = K >> 4;
    int cur = 0;
    for (int kb = 0; kb < nkb; kb++) {
        if (kb + 1 < nkb) {
            int k0 = (kb + 1) << 4;
#pragma unroll
            for (int i = 0; i < 2; i++) {
                int k = k0 + sk + i;
                ra[i] = (k < asplit) ? Ad[(long long)(m0 + sr) * ldad + k]
                                     : (double)Af[(long long)(m0 + sr) * ldaf + (k - asplit)];
                rb[i] = Bp[(long long)(n0 + sr) * ldb + k];
            }
        }
#pragma unroll
        for (int kk = 0; kk < 16; kk++) {
            double a = As[cur][ty][kk];
            c[0] = fma(a, (double)Bs[cur][tx * 4 + 0][kk], c[0]);
            c[1] = fma(a, (double)Bs[cur][tx * 4 + 1][kk], c[1]);
            c[2] = fma(a, (double)Bs[cur][tx * 4 + 2][kk], c[2]);
            c[3] = fma(a, (double)Bs[cur][tx * 4 + 3][kk], c[3]);
        }
        if (kb + 1 < nkb) {
            int nx = cur ^ 1;
#pragma unroll
            for (int i = 0; i < 2; i++) { As[nx][sr][sk + i] = ra[i]; Bs[nx][sr][sk + i] = rb[i]; }
        }
        __syncthreads();
        cur ^= 1;
    }
}

// ---------------- epilogues (register-only, 8-lane-group shuffles) ----------

__device__ void unimix_fin(const double* c, const float* bias, float* out,
                           int m0, int n0, int t) {
    const int ty = threadIdx.x >> 3, tx = threadIdx.x & 7;
    double va[4];
#pragma unroll
    for (int q = 0; q < 4; q++) va[q] = c[q] + (double)bias[n0 + tx * 4 + q];
    double mx = fmax(fmax(va[0], va[1]), fmax(va[2], va[3]));
#pragma unroll
    for (int m = 1; m < 8; m <<= 1) mx = fmax(mx, __shfl_xor(mx, m));
    double sum = 0;
#pragma unroll
    for (int q = 0; q < 4; q++) sum += exp(va[q] - mx);
#pragma unroll
    for (int m = 1; m < 8; m <<= 1) sum += __shfl_xor(sum, m);
    double rinv = 1.0 / sum;
    long long row = (long long)(m0 + ty) * 64 + t;
    float4 o;
    float* po = (float*)&o;
#pragma unroll
    for (int q = 0; q < 4; q++)
        po[q] = (float)log(0.99 * (exp(va[q] - mx) * rinv) + 0.01 / 32.0);
    *(float4*)(out + row * 1024 + n0 + tx * 4) = o;
}

__device__ void sample_fin(const double* c, const P& p, int t, int m0, int n0) {
    const int ty = threadIdx.x >> 3, tx = threadIdx.x & 7;
    int b = m0 + ty;
    double va[4];
#pragma unroll
    for (int q = 0; q < 4; q++) va[q] = c[q] + (double)p.po_b2[n0 + tx * 4 + q];
    double mx = fmax(fmax(va[0], va[1]), fmax(va[2], va[3]));
#pragma unroll
    for (int m = 1; m < 8; m <<= 1) mx = fmax(mx, __shfl_xor(mx, m));
    double sum = 0;
#pragma unroll
    for (int q = 0; q < 4; q++) sum += exp(va[q] - mx);
#pragma unroll
    for (int m = 1; m < 8; m <<= 1) sum += __shfl_xor(sum, m);
    double rinv = 1.0 / sum;
    uint32_t ka, kb;
    step_key(t, ka, kb);
    float4 o;
    float* po = (float*)&o;
    double bv = -1e300; int bc = 0;
#pragma unroll
    for (int q = 0; q < 4; q++) {
        int cc = tx * 4 + q;
        double lp = log(0.99 * (exp(va[q] - mx) * rinv) + 0.01 / 32.0);
        po[q] = (float)lp;
        double val = gumbel_d((uint32_t)(b * 1024 + n0 + cc), ka, kb) + lp;
        if (val > bv) { bv = val; bc = cc; }
    }
#pragma unroll
    for (int m = 1; m < 8; m <<= 1) {
        double ov = __shfl_xor(bv, m);
        int oc = __shfl_xor(bc, m);
        if (ov > bv || (ov == bv && oc < bc)) { bv = ov; bc = oc; }
    }
    *(float4*)(p.out_posts + ((long long)b * 64 + t) * 1024 + n0 + tx * 4) = o;
    float4 oh;
    oh.x = (tx * 4 + 0 == bc) ? 1.0f : 0.0f;
    oh.y = (tx * 4 + 1 == bc) ? 1.0f : 0.0f;
    oh.z = (tx * 4 + 2 == bc) ? 1.0f : 0.0f;
    oh.w = (tx * 4 + 3 == bc) ? 1.0f : 0.0f;
    *(float4*)(p.out_states + ((long long)b * 64 + t) * 1536 + 512 + n0 + tx * 4) = oh;
    if (tx == 0) p.sidx[b * 32 + (n0 >> 5)] = bc;
}

// ---------------- the cooperative mega kernel -------------------------------
// All phases grid-stride so any NB in {256, 512} works.

__global__ __launch_bounds__(NT, 2) void k_mega(P p) {
    __shared__ double As[2][64][17];
    __shared__ float  Bs[2][64][17];
    cg::grid_group grid = cg::this_grid();
    const int bid = blockIdx.x, tid = threadIdx.x;
    const int nb = gridDim.x;
    double c4[4];
    double c[4][4];

    // ---- P0: WT transpose, zero deter, At0 rows for t=0 ----
    for (int i = bid * NT + tid; i < 1024 * 1536; i += nb * NT) {
        int cc = i / 1536, n = i % 1536;
        p.WT[(long long)cc * 1536 + n] = p.w_ih[(long long)n * 1536 + cc];
    }
    for (int i = bid * NT + tid; i < 512 * 512; i += nb * NT) p.deter[i] = 0.0;
    for (int m = bid * 4 + (tid >> 6); m < 512; m += nb * 4)
        act_row(p.actions, p.aw, p.ab, p.ag, p.abt, p.At0 + (long long)m * 512, m, 0);
    grid.sync();

    // ---- P1: 64 sequential steps ----
    for (int t = 0; t < 64; t++) {
        const double* At = (t & 1) ? p.At1 : p.At0;
        double* Atn = (t & 1) ? p.At0 : p.At1;

        // phase A: gh 64x64 (192) + gi 64x64 (192, + one-hot gather) + act t+1 (128)
        for (int q = bid; q < 512; q += nb) {
            if (q < 192) {
                int tm = q / 24, tn = q % 24;
                int m0 = tm * 64, n0 = tn * 64;
                tile64(p.deter, 512, p.w_hh, 512, m0, n0, As, Bs, c);
                const int ty = tid >> 4, tx = tid & 15;
#pragma unroll
                for (int i = 0; i < 4; i++) {
                    long long mr = m0 + ty * 4 + i;
#pragma unroll
                    for (int j = 0; j < 4; j++) {
                        int n = n0 + tx * 4 + j;
                        p.gh[mr * 1536 + n] = c[i][j] + (double)p.b_hh[n];
                    }
                }
            } else if (q < 384) {
                int q2 = q - 192;
                int tm = q2 / 24, tn = q2 % 24;
                int m0 = tm * 64, n0 = tn * 64;
                tile64(At, 512, p.w_ih + 1024, 1536, m0, n0, As, Bs, c);
                const int ty = tid >> 4, tx = tid & 15;
                if (t > 0) {
                    // stage this tile's sidx rows into LDS (reuse As[0]: 8704B >= 8192B)
                    int* sx = (int*)&As[0][0][0];
                    __syncthreads();
                    for (int i = tid; i < 64 * 32; i += NT)
                        sx[i] = p.sidx[(m0 + (i >> 5)) * 32 + (i & 31)];
                    __syncthreads();
#pragma unroll
                    for (int i = 0; i < 4; i++) {
                        int r = ty * 4 + i;
                        for (int s = 0; s < 32; s++) {
                            int cc = s * 32 + sx[r * 32 + s];
                            const float4 v = *(const float4*)(p.WT + (long long)cc * 1536 + n0 + tx * 4);
                            c[i][0] += (double)v.x; c[i][1] += (double)v.y;
                            c[i][2] += (double)v.z; c[i][3] += (double)v.w;
                        }
                    }
                    __syncthreads();
                }
#pragma unroll
                for (int i = 0; i < 4; i++) {
                    long long mr = m0 + ty * 4 + i;
#pragma unroll
                    for (int j = 0; j < 4; j++) {
                        int n = n0 + tx * 4 + j;
                        p.gi[mr * 1536 + n] = c[i][j] + (double)p.b_ih[n];
                    }
                }
            } else {
                if (t < 63) {
                    int rr = (q - 384) * 4 + (tid >> 6);
                    act_row(p.actions, p.aw, p.ab, p.ag, p.abt,
                            Atn + (long long)rr * 512, rr, t + 1);
                }
            }
        }
        grid.sync();

        // phase B: GRU pointwise
        for (int e = bid * NT + tid; e < 512 * 512; e += nb * NT) {
            int b = e >> 9, d = e & 511;
            long long base = (long long)b * 1536;
            double ir = p.gi[base + d],          hr = p.gh[base + d];
            double iz = p.gi[base + 512 + d],    hz = p.gh[base + 512 + d];
            double in_ = p.gi[base + 1024 + d],  hn = p.gh[base + 1024 + d];
            double h = p.deter[e];
            double rr = 1.0 / (1.0 + exp(-(ir + hr)));
            double zz = 1.0 / (1.0 + exp(-(iz + hz)));
            double nn = tanh(in_ + rr * hn);
            double dn = (1.0 - zz) * nn + zz * h;
            p.deter[e] = dn;
            p.out_states[((long long)b * 64 + t) * 1536 + d] = (float)dn;
        }
        grid.sync();

        // phase C: posterior hidden (K=1024, 256 tiles) + prior hidden (256 tiles)
        for (int q = bid; q < 512; q += nb) {
            if (q < 256) {
                int tm = q >> 4, tn = q & 15;
                tile32(p.deter, 512, p.embeds + (long long)t * 512, 32768, 512,
                       p.po_w1, 1024, 1024, tm * 32, tn * 32, As, Bs, c4);
                const int ty = tid >> 3, tx = tid & 7;
#pragma unroll
                for (int j = 0; j < 4; j++)
                    p.POraw[(long long)(tm * 32 + ty) * 512 + tn * 32 + tx * 4 + j] =
                        c4[j] + (double)p.po_b1[tn * 32 + tx * 4 + j];
            } else {
                int q2 = q - 256;
                int tm = q2 >> 4, tn = q2 & 15;
                tile32(p.deter, 512, nullptr, 0, 512, p.pr_w1, 512, 512,
                       tm * 32, tn * 32, As, Bs, c4);
                const int ty = tid >> 3, tx = tid & 7;
#pragma unroll
                for (int j = 0; j < 4; j++)
                    p.PRraw[(long long)(tm * 32 + ty) * 512 + tn * 32 + tx * 4 + j] =
                        c4[j] + (double)p.pr_b1[tn * 32 + tx * 4 + j];
            }
        }
        grid.sync();

        // phase D: LN+mish rows (512 po + 512 pr)
        for (int r = bid * 4 + (tid >> 6); r < 1024; r += nb * 4) {
            if (r < 512) ln_row(p.POraw + (long long)r * 512, p.po_g, p.po_bt);
            else         ln_row(p.PRraw + (long long)(r - 512) * 512, p.pr_g, p.pr_bt);
        }
        grid.sync();

        // phase E: posterior out + sample (512) ; prior out + unimix (512)
        for (int q = bid; q < 1024; q += nb) {
            if (q < 512) {
                int tm = q >> 5, s = q & 31;
                tile32(p.POraw, 512, nullptr, 0, 512, p.po_w2, 512, 512,
                       tm * 32, s * 32, As, Bs, c4);
                sample_fin(c4, p, t, tm * 32, s * 32);
            } else {
                int q2 = q - 512;
                int tm = q2 >> 5, s = q2 & 31;
                tile32(p.PRraw, 512, nullptr, 0, 512, p.pr_w2, 512, 512,
                       tm * 32, s * 32, As, Bs, c4);
                unimix_fin(c4, p.pr_b2, p.out_priors, tm * 32, s * 32, t);
            }
        }
        grid.sync();
    }
}

// ---------------- host -------------------------------------------------------

extern "C" void kernel_launch(void* const* d_in, const int* in_sizes, int n_in,
                              void* d_out, int out_size, void* d_ws, size_t ws_size,
                              hipStream_t stream) {
    P p;
    p.actions = (const float*)d_in[0];
    p.embeds  = (const float*)d_in[1];
    p.aw = (const float*)d_in[2];  p.ab = (const float*)d_in[3];
    p.ag = (const float*)d_in[4];  p.abt = (const float*)d_in[5];
    p.w_ih = (const float*)d_in[6]; p.w_hh = (const float*)d_in[7];
    p.b_ih = (const float*)d_in[8]; p.b_hh = (const float*)d_in[9];
    p.pr_w1 = (const float*)d_in[10]; p.pr_b1 = (const float*)d_in[11];
    p.pr_g = (const float*)d_in[12];  p.pr_bt = (const float*)d_in[13];
    p.pr_w2 = (const float*)d_in[14]; p.pr_b2 = (const float*)d_in[15];
    p.po_w1 = (const float*)d_in[16]; p.po_b1 = (const float*)d_in[17];
    p.po_g = (const float*)d_in[18];  p.po_bt = (const float*)d_in[19];
    p.po_w2 = (const float*)d_in[20]; p.po_b2 = (const float*)d_in[21];

    float* out = (float*)d_out;
    p.out_states = out;
    p.out_priors = out + (size_t)512 * 64 * 1536;
    p.out_posts  = out + (size_t)512 * 64 * 1536 + (size_t)512 * 64 * 1024;

    char* ws = (char*)d_ws;
    size_t off = 0;
    auto carve = [&](size_t bytes) -> char* {
        char* q = ws + off;
        off = (off + bytes + 255) & ~(size_t)255;
        return q;
    };
    p.sidx  = (int*)carve((size_t)512 * 32 * 4);
    p.WT    = (float*)carve((size_t)1024 * 1536 * 4);
    p.deter = (double*)carve((size_t)512 * 512 * 8);
    p.gh    = (double*)carve((size_t)512 * 1536 * 8);
    p.gi    = (double*)carve((size_t)512 * 1536 * 8);
    p.POraw = (double*)carve((size_t)512 * 512 * 8);
    p.PRraw = (double*)carve((size_t)512 * 512 * 8);
    p.At0   = (double*)carve((size_t)512 * 512 * 8);
    p.At1   = (double*)carve((size_t)512 * 512 * 8);
    if (off > ws_size) return;  // fast visible failure

    // Pick a grid that the cooperative-launch validator will accept.
    int maxb = 0;
    hipError_t oe = hipOccupancyMaxActiveBlocksPerMultiprocessor(
        &maxb, (const void*)k_mega, NT, 0);
    int nb = (oe == hipSuccess && maxb >= 2) ? 512 : 256;

    void* args[] = { (void*)&p };
    hipLaunchCooperativeKernel((const void*)k_mega, dim3(nb), dim3(NT),
                               args, 0, stream);
}

// Round 12
// 35149.838 us; speedup vs baseline: 1.2610x; 1.0639x over previous
//
#include <hip/hip_runtime.h>
#include <hip/hip_cooperative_groups.h>
#include <stdint.h>

namespace cg = cooperative_groups;

#define NT 256

struct P {
    const float *actions, *embeds, *aw, *ab, *ag, *abt;
    const float *w_ih, *w_hh, *b_ih, *b_hh;
    const float *pr_w1, *pr_b1, *pr_g, *pr_bt, *pr_w2, *pr_b2;
    const float *po_w1, *po_b1, *po_g, *po_bt, *po_w2, *po_b2;
    float *out_states, *out_priors, *out_posts;
    float *WT;          // [1024][1536] w_ih stoch-part transposed
    double *deter;      // [512][512]
    double *gh, *gi;    // [512][1536]
    double *POraw;      // [512][512]
    double *PRraw;      // [512][512]
    double *At0, *At1;  // [512][512]
    int *sidx;          // [512*32]
};

// ---------------- math helpers (f64) ---------------------------------------

__device__ __forceinline__ double mish_d(double x) {
    double sp = fmax(x, 0.0) + log1p(exp(-fabs(x)));
    return x * tanh(sp);
}

// ---------------- threefry2x32 (JAX partitionable semantics) ----------------

__device__ __forceinline__ uint32_t rotl32(uint32_t v, int r) {
    return (v << r) | (v >> (32 - r));
}

__device__ __forceinline__ void tf2x32(uint32_t k0, uint32_t k1, uint32_t& x0, uint32_t& x1) {
    const uint32_t ks2 = k0 ^ k1 ^ 0x1BD11BDAu;
    const int ra[4] = {13, 15, 26, 6};
    const int rb[4] = {17, 29, 16, 24};
    x0 += k0; x1 += k1;
#pragma unroll
    for (int i = 0; i < 4; i++) { x0 += x1; x1 = rotl32(x1, ra[i]); x1 ^= x0; }
    x0 += k1; x1 += ks2 + 1u;
#pragma unroll
    for (int i = 0; i < 4; i++) { x0 += x1; x1 = rotl32(x1, rb[i]); x1 ^= x0; }
    x0 += ks2; x1 += k0 + 2u;
#pragma unroll
    for (int i = 0; i < 4; i++) { x0 += x1; x1 = rotl32(x1, ra[i]); x1 ^= x0; }
    x0 += k0; x1 += k1 + 3u;
#pragma unroll
    for (int i = 0; i < 4; i++) { x0 += x1; x1 = rotl32(x1, rb[i]); x1 ^= x0; }
    x0 += k1; x1 += ks2 + 4u;
#pragma unroll
    for (int i = 0; i < 4; i++) { x0 += x1; x1 = rotl32(x1, ra[i]); x1 ^= x0; }
    x0 += ks2; x1 += k0 + 5u;
}

__device__ __forceinline__ void step_key(int t, uint32_t& ka, uint32_t& kb) {
    uint32_t x0 = 0u, x1 = (uint32_t)t;
    tf2x32(0u, 42u, x0, x1);
    ka = x0; kb = x1;
}

__device__ __forceinline__ double gumbel_d(uint32_t n, uint32_t ka, uint32_t kb) {
    uint32_t x0 = 0u, x1 = n;
    tf2x32(ka, kb, x0, x1);
    uint32_t bits = x0 ^ x1;
    uint32_t fb = (bits >> 9) | 0x3f800000u;
    float f = __uint_as_float(fb) - 1.0f;
    double u = fmax((double)f, 1.17549435e-38);
    return -log(-log(u));
}

// ---------------- per-wave row ops ------------------------------------------

__device__ void act_row(const float* actions, const float* aw, const float* ab,
                        const float* ag, const float* abt, double* dst, int b, int t) {
    int l = threadIdx.x & 63;
    double x[8];
    double s = 0;
#pragma unroll
    for (int i = 0; i < 8; i++) {
        int h = l + 64 * i;
        double a = (double)ab[h];
        if (t > 0) {
            const float* ac = actions + ((long long)b * 64 + (t - 1)) * 32;
            #pragma unroll 4
            for (int k = 0; k < 32; k++)
                a += (double)ac[k] * (double)aw[h * 32 + k];
        }
        x[i] = a; s += a;
    }
#pragma unroll
    for (int m = 1; m < 64; m <<= 1) s += __shfl_xor(s, m);
    double mean = s * (1.0 / 512.0);
    double vv = 0;
#pragma unroll
    for (int i = 0; i < 8; i++) { double d = x[i] - mean; vv += d * d; }
#pragma unroll
    for (int m = 1; m < 64; m <<= 1) vv += __shfl_xor(vv, m);
    double inv = 1.0 / sqrt(vv * (1.0 / 512.0) + 1e-5);
#pragma unroll
    for (int i = 0; i < 8; i++) {
        int h = l + 64 * i;
        dst[h] = mish_d((x[i] - mean) * inv * (double)ag[h] + (double)abt[h]);
    }
}

__device__ void ln_row(double* row, const float* g, const float* bt) {
    int l = threadIdx.x & 63;
    double x[8];
    double s = 0;
#pragma unroll
    for (int i = 0; i < 8; i++) { x[i] = row[l + 64 * i]; s += x[i]; }
#pragma unroll
    for (int m = 1; m < 64; m <<= 1) s += __shfl_xor(s, m);
    double mean = s * (1.0 / 512.0);
    double vv = 0;
#pragma unroll
    for (int i = 0; i < 8; i++) { double d = x[i] - mean; vv += d * d; }
#pragma unroll
    for (int m = 1; m < 64; m <<= 1) vv += __shfl_xor(vv, m);
    double inv = 1.0 / sqrt(vv * (1.0 / 512.0) + 1e-5);
#pragma unroll
    for (int i = 0; i < 8; i++) {
        int h = l + 64 * i;
        row[h] = mish_d((x[i] - mean) * inv * (double)g[h] + (double)bt[h]);
    }
}

// ---------------- 64x32 tile, K=512, dbuf slice=8 (vector f64) --------------
// C[m][n] = sum_k A[m][k]*B[n][k]; thread (ty=tid>>3 0..31, tx=tid&7) owns
// rows m0+ty*2+{0,1}, cols n0+tx*4+{0..3} -> c[2][4].
// LDS (flat): A stride 9 (64 rows), B stride 9 (32 rows).

__device__ void tile6432(const double* __restrict__ Ad, long long lda,
                         const float* __restrict__ Bp, long long ldb,
                         int m0, int n0,
                         double (&AsD)[2][640], float (&BsF)[2][640],
                         double (&c)[2][4]) {
    const int tid = threadIdx.x;
    const int ty = tid >> 3, tx = tid & 7;
    const int ar = tid >> 2, ak = (tid & 3) * 2;   // A: 64 rows x 8k, 2/thread
    const int br = tid >> 3, bk = tid & 7;         // B: 32 rows x 8k, 1/thread
#pragma unroll
    for (int i = 0; i < 2; i++)
#pragma unroll
        for (int j = 0; j < 4; j++) c[i][j] = 0.0;
    double ra[2]; float rb;
#pragma unroll
    for (int i = 0; i < 2; i++) ra[i] = Ad[(long long)(m0 + ar) * lda + ak + i];
    rb = Bp[(long long)(n0 + br) * ldb + bk];
#pragma unroll
    for (int i = 0; i < 2; i++) AsD[0][ar * 9 + ak + i] = ra[i];
    BsF[0][br * 9 + bk] = rb;
    __syncthreads();
    int cur = 0;
    for (int kb = 0; kb < 64; kb++) {
        if (kb < 63) {
            int k0 = (kb + 1) * 8;
#pragma unroll
            for (int i = 0; i < 2; i++) ra[i] = Ad[(long long)(m0 + ar) * lda + k0 + ak + i];
            rb = Bp[(long long)(n0 + br) * ldb + k0 + bk];
        }
#pragma unroll
        for (int kk = 0; kk < 8; kk++) {
            double av[2], bv[4];
#pragma unroll
            for (int i = 0; i < 2; i++) av[i] = AsD[cur][(ty * 2 + i) * 9 + kk];
#pragma unroll
            for (int j = 0; j < 4; j++) bv[j] = (double)BsF[cur][(tx * 4 + j) * 9 + kk];
#pragma unroll
            for (int i = 0; i < 2; i++)
#pragma unroll
                for (int j = 0; j < 4; j++) c[i][j] = fma(av[i], bv[j], c[i][j]);
        }
        if (kb < 63) {
            int nx = cur ^ 1;
#pragma unroll
            for (int i = 0; i < 2; i++) AsD[nx][ar * 9 + ak + i] = ra[i];
            BsF[nx][br * 9 + bk] = rb;
        }
        __syncthreads();
        cur ^= 1;
    }
}

// ---------------- 32x32 tile, generic K, dbuf slice=16 (vector f64) ---------
// A: k<asplit from Ad (f64), else Af (f32). thread (ty=tid>>3, tx=tid&7)
// owns row m0+ty, cols n0+tx*4..+3 -> c[4]. LDS stride 17 (32 rows).

__device__ void tile32(const double* Ad, long long ldad,
                       const float* Af, long long ldaf, int asplit,
                       const float* Bp, long long ldb, int K,
                       int m0, int n0,
                       double (&AsD)[2][640], float (&BsF)[2][640],
                       double* c) {
    const int tid = threadIdx.x;
    const int ty = tid >> 3, tx = tid & 7;
    const int sr = tid >> 3, sk = (tid & 7) * 2;
    double ra[2]; float rb[2];
#pragma unroll
    for (int i = 0; i < 2; i++) {
        int k = sk + i;
        ra[i] = (k < asplit) ? Ad[(long long)(m0 + sr) * ldad + k]
                             : (double)Af[(long long)(m0 + sr) * ldaf + (k - asplit)];
        rb[i] = Bp[(long long)(n0 + sr) * ldb + k];
    }
#pragma unroll
    for (int i = 0; i < 2; i++) { AsD[0][sr * 17 + sk + i] = ra[i]; BsF[0][sr * 17 + sk + i] = rb[i]; }
    __syncthreads();
    c[0] = c[1] = c[2] = c[3] = 0.0;
    const int nkb = K >> 4;
    int cur = 0;
    for (int kb = 0; kb < nkb; kb++) {
        if (kb + 1 < nkb) {
            int k0 = (kb + 1) << 4;
#pragma unroll
            for (int i = 0; i < 2; i++) {
                int k = k0 + sk + i;
                ra[i] = (k < asplit) ? Ad[(long long)(m0 + sr) * ldad + k]
                                     : (double)Af[(long long)(m0 + sr) * ldaf + (k - asplit)];
                rb[i] = Bp[(long long)(n0 + sr) * ldb + k];
            }
        }
#pragma unroll
        for (int kk = 0; kk < 16; kk++) {
            double a = AsD[cur][ty * 17 + kk];
            c[0] = fma(a, (double)BsF[cur][(tx * 4 + 0) * 17 + kk], c[0]);
            c[1] = fma(a, (double)BsF[cur][(tx * 4 + 1) * 17 + kk], c[1]);
            c[2] = fma(a, (double)BsF[cur][(tx * 4 + 2) * 17 + kk], c[2]);
            c[3] = fma(a, (double)BsF[cur][(tx * 4 + 3) * 17 + kk], c[3]);
        }
        if (kb + 1 < nkb) {
            int nx = cur ^ 1;
#pragma unroll
            for (int i = 0; i < 2; i++) { AsD[nx][sr * 17 + sk + i] = ra[i]; BsF[nx][sr * 17 + sk + i] = rb[i]; }
        }
        __syncthreads();
        cur ^= 1;
    }
}

// ---------------- epilogues (register-only, 8-lane-group shuffles) ----------

__device__ void unimix_fin(const double* c, const float* bias, float* out,
                           int m0, int n0, int t) {
    const int ty = threadIdx.x >> 3, tx = threadIdx.x & 7;
    double va[4];
#pragma unroll
    for (int q = 0; q < 4; q++) va[q] = c[q] + (double)bias[n0 + tx * 4 + q];
    double mx = fmax(fmax(va[0], va[1]), fmax(va[2], va[3]));
#pragma unroll
    for (int m = 1; m < 8; m <<= 1) mx = fmax(mx, __shfl_xor(mx, m));
    double sum = 0;
#pragma unroll
    for (int q = 0; q < 4; q++) sum += exp(va[q] - mx);
#pragma unroll
    for (int m = 1; m < 8; m <<= 1) sum += __shfl_xor(sum, m);
    double rinv = 1.0 / sum;
    long long row = (long long)(m0 + ty) * 64 + t;
    float4 o;
    float* po = (float*)&o;
#pragma unroll
    for (int q = 0; q < 4; q++)
        po[q] = (float)log(0.99 * (exp(va[q] - mx) * rinv) + 0.01 / 32.0);
    *(float4*)(out + row * 1024 + n0 + tx * 4) = o;
}

__device__ void sample_fin(const double* c, const P& p, int t, int m0, int n0) {
    const int ty = threadIdx.x >> 3, tx = threadIdx.x & 7;
    int b = m0 + ty;
    double va[4];
#pragma unroll
    for (int q = 0; q < 4; q++) va[q] = c[q] + (double)p.po_b2[n0 + tx * 4 + q];
    double mx = fmax(fmax(va[0], va[1]), fmax(va[2], va[3]));
#pragma unroll
    for (int m = 1; m < 8; m <<= 1) mx = fmax(mx, __shfl_xor(mx, m));
    double sum = 0;
#pragma unroll
    for (int q = 0; q < 4; q++) sum += exp(va[q] - mx);
#pragma unroll
    for (int m = 1; m < 8; m <<= 1) sum += __shfl_xor(sum, m);
    double rinv = 1.0 / sum;
    uint32_t ka, kb;
    step_key(t, ka, kb);
    float4 o;
    float* po = (float*)&o;
    double bv = -1e300; int bc = 0;
#pragma unroll
    for (int q = 0; q < 4; q++) {
        int cc = tx * 4 + q;
        double lp = log(0.99 * (exp(va[q] - mx) * rinv) + 0.01 / 32.0);
        po[q] = (float)lp;
        double val = gumbel_d((uint32_t)(b * 1024 + n0 + cc), ka, kb) + lp;
        if (val > bv) { bv = val; bc = cc; }
    }
#pragma unroll
    for (int m = 1; m < 8; m <<= 1) {
        double ov = __shfl_xor(bv, m);
        int oc = __shfl_xor(bc, m);
        if (ov > bv || (ov == bv && oc < bc)) { bv = ov; bc = oc; }
    }
    *(float4*)(p.out_posts + ((long long)b * 64 + t) * 1024 + n0 + tx * 4) = o;
    float4 oh;
    oh.x = (tx * 4 + 0 == bc) ? 1.0f : 0.0f;
    oh.y = (tx * 4 + 1 == bc) ? 1.0f : 0.0f;
    oh.z = (tx * 4 + 2 == bc) ? 1.0f : 0.0f;
    oh.w = (tx * 4 + 3 == bc) ? 1.0f : 0.0f;
    *(float4*)(p.out_states + ((long long)b * 64 + t) * 1536 + 512 + n0 + tx * 4) = oh;
    if (tx == 0) p.sidx[b * 32 + (n0 >> 5)] = bc;
}

// ---------------- the cooperative mega kernel -------------------------------
// All phases grid-stride so any NB in {256, 512, 768, 1024} works.

__global__ __launch_bounds__(NT, 4) void k_mega(P p) {
    __shared__ double AsD[2][640];
    __shared__ float  BsF[2][640];
    cg::grid_group grid = cg::this_grid();
    const int bid = blockIdx.x, tid = threadIdx.x;
    const int nb = gridDim.x;
    double c4[4];
    double c[2][4];

    // ---- P0: WT transpose, zero deter, At0 rows for t=0 ----
    for (int i = bid * NT + tid; i < 1024 * 1536; i += nb * NT) {
        int cc = i / 1536, n = i % 1536;
        p.WT[(long long)cc * 1536 + n] = p.w_ih[(long long)n * 1536 + cc];
    }
    for (int i = bid * NT + tid; i < 512 * 512; i += nb * NT) p.deter[i] = 0.0;
    for (int m = bid * 4 + (tid >> 6); m < 512; m += nb * 4)
        act_row(p.actions, p.aw, p.ab, p.ag, p.abt, p.At0 + (long long)m * 512, m, 0);
    grid.sync();

    // ---- P1: 64 sequential steps ----
    for (int t = 0; t < 64; t++) {
        const double* At = (t & 1) ? p.At1 : p.At0;
        double* Atn = (t & 1) ? p.At0 : p.At1;

        // phase A: gh 64x32 (384) + gi 64x32 (384, + one-hot gather) + act t+1 (128)
        for (int q = bid; q < 896; q += nb) {
            if (q < 384) {
                int tm = q / 48, tn = q % 48;
                int m0 = tm * 64, n0 = tn * 32;
                tile6432(p.deter, 512, p.w_hh, 512, m0, n0, AsD, BsF, c);
                const int ty = tid >> 3, tx = tid & 7;
#pragma unroll
                for (int i = 0; i < 2; i++) {
                    long long mr = m0 + ty * 2 + i;
#pragma unroll
                    for (int j = 0; j < 4; j++) {
                        int n = n0 + tx * 4 + j;
                        p.gh[mr * 1536 + n] = c[i][j] + (double)p.b_hh[n];
                    }
                }
            } else if (q < 768) {
                int q2 = q - 384;
                int tm = q2 / 48, tn = q2 % 48;
                int m0 = tm * 64, n0 = tn * 32;
                tile6432(At, 512, p.w_ih + 1024, 1536, m0, n0, AsD, BsF, c);
                const int ty = tid >> 3, tx = tid & 7;
                if (t > 0) {
                    // stage this tile's sidx rows into LDS (flat AsD = 10240B >= 8192B)
                    int* sx = (int*)&AsD[0][0];
                    __syncthreads();
                    for (int i = tid; i < 64 * 32; i += NT)
                        sx[i] = p.sidx[(m0 + (i >> 5)) * 32 + (i & 31)];
                    __syncthreads();
#pragma unroll
                    for (int i = 0; i < 2; i++) {
                        int r = ty * 2 + i;
                        for (int s = 0; s < 32; s++) {
                            int cc = s * 32 + sx[r * 32 + s];
                            const float4 v = *(const float4*)(p.WT + (long long)cc * 1536 + n0 + tx * 4);
                            c[i][0] += (double)v.x; c[i][1] += (double)v.y;
                            c[i][2] += (double)v.z; c[i][3] += (double)v.w;
                        }
                    }
                    __syncthreads();
                }
#pragma unroll
                for (int i = 0; i < 2; i++) {
                    long long mr = m0 + ty * 2 + i;
#pragma unroll
                    for (int j = 0; j < 4; j++) {
                        int n = n0 + tx * 4 + j;
                        p.gi[mr * 1536 + n] = c[i][j] + (double)p.b_ih[n];
                    }
                }
            } else {
                if (t < 63) {
                    int rr = (q - 768) * 4 + (tid >> 6);
                    act_row(p.actions, p.aw, p.ab, p.ag, p.abt,
                            Atn + (long long)rr * 512, rr, t + 1);
                }
            }
        }
        grid.sync();

        // phase B: GRU pointwise
        for (int e = bid * NT + tid; e < 512 * 512; e += nb * NT) {
            int b = e >> 9, d = e & 511;
            long long base = (long long)b * 1536;
            double ir = p.gi[base + d],          hr = p.gh[base + d];
            double iz = p.gi[base + 512 + d],    hz = p.gh[base + 512 + d];
            double in_ = p.gi[base + 1024 + d],  hn = p.gh[base + 1024 + d];
            double h = p.deter[e];
            double rr = 1.0 / (1.0 + exp(-(ir + hr)));
            double zz = 1.0 / (1.0 + exp(-(iz + hz)));
            double nn = tanh(in_ + rr * hn);
            double dn = (1.0 - zz) * nn + zz * h;
            p.deter[e] = dn;
            p.out_states[((long long)b * 64 + t) * 1536 + d] = (float)dn;
        }
        grid.sync();

        // phase C: posterior hidden (K=1024, 256 tiles) + prior hidden (256 tiles)
        for (int q = bid; q < 512; q += nb) {
            if (q < 256) {
                int tm = q >> 4, tn = q & 15;
                tile32(p.deter, 512, p.embeds + (long long)t * 512, 32768, 512,
                       p.po_w1, 1024, 1024, tm * 32, tn * 32, AsD, BsF, c4);
                const int ty = tid >> 3, tx = tid & 7;
#pragma unroll
                for (int j = 0; j < 4; j++)
                    p.POraw[(long long)(tm * 32 + ty) * 512 + tn * 32 + tx * 4 + j] =
                        c4[j] + (double)p.po_b1[tn * 32 + tx * 4 + j];
            } else {
                int q2 = q - 256;
                int tm = q2 >> 4, tn = q2 & 15;
                tile32(p.deter, 512, nullptr, 0, 512, p.pr_w1, 512, 512,
                       tm * 32, tn * 32, AsD, BsF, c4);
                const int ty = tid >> 3, tx = tid & 7;
#pragma unroll
                for (int j = 0; j < 4; j++)
                    p.PRraw[(long long)(tm * 32 + ty) * 512 + tn * 32 + tx * 4 + j] =
                        c4[j] + (double)p.pr_b1[tn * 32 + tx * 4 + j];
            }
        }
        grid.sync();

        // phase D: LN+mish rows (512 po + 512 pr)
        for (int r = bid * 4 + (tid >> 6); r < 1024; r += nb * 4) {
            if (r < 512) ln_row(p.POraw + (long long)r * 512, p.po_g, p.po_bt);
            else         ln_row(p.PRraw + (long long)(r - 512) * 512, p.pr_g, p.pr_bt);
        }
        grid.sync();

        // phase E: posterior out + sample (512) ; prior out + unimix (512)
        for (int q = bid; q < 1024; q += nb) {
            if (q < 512) {
                int tm = q >> 5, s = q & 31;
                tile32(p.POraw, 512, nullptr, 0, 512, p.po_w2, 512, 512,
                       tm * 32, s * 32, AsD, BsF, c4);
                sample_fin(c4, p, t, tm * 32, s * 32);
            } else {
                int q2 = q - 512;
                int tm = q2 >> 5, s = q2 & 31;
                tile32(p.PRraw, 512, nullptr, 0, 512, p.pr_w2, 512, 512,
                       tm * 32, s * 32, AsD, BsF, c4);
                unimix_fin(c4, p.pr_b2, p.out_priors, tm * 32, s * 32, t);
            }
        }
        grid.sync();
    }
}

// ---------------- host -------------------------------------------------------

extern "C" void kernel_launch(void* const* d_in, const int* in_sizes, int n_in,
                              void* d_out, int out_size, void* d_ws, size_t ws_size,
                              hipStream_t stream) {
    P p;
    p.actions = (const float*)d_in[0];
    p.embeds  = (const float*)d_in[1];
    p.aw = (const float*)d_in[2];  p.ab = (const float*)d_in[3];
    p.ag = (const float*)d_in[4];  p.abt = (const float*)d_in[5];
    p.w_ih = (const float*)d_in[6]; p.w_hh = (const float*)d_in[7];
    p.b_ih = (const float*)d_in[8]; p.b_hh = (const float*)d_in[9];
    p.pr_w1 = (const float*)d_in[10]; p.pr_b1 = (const float*)d_in[11];
    p.pr_g = (const float*)d_in[12];  p.pr_bt = (const float*)d_in[13];
    p.pr_w2 = (const float*)d_in[14]; p.pr_b2 = (const float*)d_in[15];
    p.po_w1 = (const float*)d_in[16]; p.po_b1 = (const float*)d_in[17];
    p.po_g = (const float*)d_in[18];  p.po_bt = (const float*)d_in[19];
    p.po_w2 = (const float*)d_in[20]; p.po_b2 = (const float*)d_in[21];

    float* out = (float*)d_out;
    p.out_states = out;
    p.out_priors = out + (size_t)512 * 64 * 1536;
    p.out_posts  = out + (size_t)512 * 64 * 1536 + (size_t)512 * 64 * 1024;

    char* ws = (char*)d_ws;
    size_t off = 0;
    auto carve = [&](size_t bytes) -> char* {
        char* q = ws + off;
        off = (off + bytes + 255) & ~(size_t)255;
        return q;
    };
    p.sidx  = (int*)carve((size_t)512 * 32 * 4);
    p.WT    = (float*)carve((size_t)1024 * 1536 * 4);
    p.deter = (double*)carve((size_t)512 * 512 * 8);
    p.gh    = (double*)carve((size_t)512 * 1536 * 8);
    p.gi    = (double*)carve((size_t)512 * 1536 * 8);
    p.POraw = (double*)carve((size_t)512 * 512 * 8);
    p.PRraw = (double*)carve((size_t)512 * 512 * 8);
    p.At0   = (double*)carve((size_t)512 * 512 * 8);
    p.At1   = (double*)carve((size_t)512 * 512 * 8);
    if (off > ws_size) return;  // fast visible failure

    // Pick the largest grid the cooperative-launch validator will accept.
    int maxb = 0;
    hipError_t oe = hipOccupancyMaxActiveBlocksPerMultiprocessor(
        &maxb, (const void*)k_mega, NT, 0);
    if (oe != hipSuccess || maxb < 1) maxb = 1;
    if (maxb > 4) maxb = 4;
    int nb = 256 * maxb;

    void* args[] = { (void*)&p };
    hipLaunchCooperativeKernel((const void*)k_mega, dim3(nb), dim3(NT),
                               args, 0, stream);
}